// Round 12
// baseline (3539.901 us; speedup 1.0000x reference)
//
#include <hip/hip_runtime.h>
#include <math.h>

// Problem constants
#define T_IN   256
#define T_OUT  256
#define D_     128
#define U_     256
#define NSTEP  511

// 16 groups x 2 chains; 16 WGs per group; 256 threads/WG; 256 WGs total (1/CU)
#define NWG    16
#define NCH    2
#define NGRP   16
#define THREADS 256

// ws per group in u64 units (tagged words: hi32 = tag, lo32 = payload):
//   g_h0 [2 slot][2 ch][128]  @ 0
//   g_h1                      @ 512
//   g_h2                      @ 1024
//   g_pd [2 slot][16 src][2 ch][128] @ 1536   (fp32 dense partials)
// R12 delta vs verified R11 (protocol/layout/tags IDENTICAL):
//   - fused gathers: issue all initial loads back-to-back, poll after
//   - overlap U-matmuls moved BETWEEN load-issue and poll (hide RTT)
//   - sx2 = h0+h1 fused into h1-gather (gathered) and do_final(1) (own)
#define G64_H0   0
#define G64_H1   512
#define G64_H2   1024
#define G64_PD   1536
#define GRPSTRIDE64 10240
#define WS_NEED  (NGRP * GRPSTRIDE64 * 8)   // 1,310,720 B

typedef _Float16 half8 __attribute__((ext_vector_type(8)));
typedef float    f32x4 __attribute__((ext_vector_type(4)));

__device__ __forceinline__ float sigmoidf_(float x) { return 1.0f / (1.0f + __expf(-x)); }
__device__ __forceinline__ unsigned pk(float a, float b) {
    union { _Float16 h[2]; unsigned u; } v;
    v.h[0] = (_Float16)a; v.h[1] = (_Float16)b; return v.u;
}
__device__ __forceinline__ float2 upk(unsigned x) {
    union { unsigned u; _Float16 h[2]; } v; v.u = x;
    return make_float2((float)v.h[0], (float)v.h[1]);
}

__global__ void zero_ws(unsigned* p, int n) {
    int i = blockIdx.x * 256 + threadIdx.x;
    if (i < n) p[i] = 0;
}

__device__ __forceinline__ f32x4 mm_k(const unsigned* xb, const _Float16* wb,
                                      int nks, f32x4 acc) {
    #pragma unroll
    for (int ks = 0; ks < nks; ++ks) {
        half8 a = *(const half8*)(const void*)(xb + ks * 16);
        half8 b = *(const half8*)(const void*)(wb + ks * 32);
        acc = __builtin_amdgcn_mfma_f32_16x16x32_f16(a, b, acc, 0, 0, 0);
    }
    return acc;
}

__global__ __launch_bounds__(THREADS) void gru_dist(
    const float* __restrict__ inputs, const float* __restrict__ noise,
    const float* __restrict__ h_init,
    const float* __restrict__ W0, const float* __restrict__ U0, const float* __restrict__ b0,
    const float* __restrict__ W1, const float* __restrict__ U1, const float* __restrict__ b1,
    const float* __restrict__ W2, const float* __restrict__ U2, const float* __restrict__ b2,
    const float* __restrict__ Wd, const float* __restrict__ bd,
    unsigned long long* __restrict__ ws, float* __restrict__ out)
{
    const int bid  = blockIdx.x;
    const int grp  = bid & 15;      // group's 16 WGs share bid%8 -> same XCD (perf heuristic)
    const int w    = bid >> 4;      // wg-in-group 0..15
    const int t    = threadIdx.x;
    const int lane = t & 63;
    const int wv   = t >> 6;
    const int u16  = lane & 15, kg = lane >> 4, ch2 = u16 & 1;

    // ---- LDS (~158 KB) ----
    __shared__ __align__(16) _Float16 lw0[48 * 136];
    __shared__ __align__(16) _Float16 lu0[48 * 264];
    __shared__ __align__(16) _Float16 lw1[48 * 264];
    __shared__ __align__(16) _Float16 lu1[48 * 264];
    __shared__ __align__(16) _Float16 lw2[48 * 264];
    __shared__ __align__(16) _Float16 lu2[48 * 264];
    __shared__ __align__(16) _Float16 lwdk[128 * 32];  // [n][own-k 0..31], k>=16 zero
    __shared__ __align__(16) _Float16 sxd[16 * 32];    // dense A (rows 0,1 = chains)
    __shared__ __align__(16) unsigned sx0[NCH][68];
    __shared__ __align__(16) unsigned sh0[2][NCH][132];
    __shared__ __align__(16) unsigned sh1[NCH][132];
    __shared__ __align__(16) unsigned sh2[NCH][132];
    __shared__ __align__(16) unsigned sx2[NCH][132];
    __shared__ float sgx[3][192];
    __shared__ float sgh[3][192];
    __shared__ float sb[3][2][48];
    __shared__ float sbdf[128];
    __shared__ float spredf[NCH][128];

    unsigned long long* gbase = ws + (size_t)grp * GRPSTRIDE64;
    unsigned long long* g_h0 = gbase + G64_H0;
    unsigned long long* g_h1 = gbase + G64_H1;
    unsigned long long* g_h2 = gbase + G64_H2;
    unsigned long long* g_pd = gbase + G64_PD;

    // ---- one-time preload ----
    {
        const float* srcs[6] = {W0, U0, W1, U1, W2, U2};
        _Float16*    dsts[6] = {lw0, lu0, lw1, lu1, lw2, lu2};
        const int Ks[6] = {128, 256, 256, 256, 256, 256};
        const int Ss[6] = {136, 264, 264, 264, 264, 264};
        for (int m = 0; m < 6; ++m) {
            const float* s = srcs[m]; _Float16* d = dsts[m];
            const int K = Ks[m], S = Ss[m];
            for (int idx = t; idx < 48 * K; idx += THREADS) {
                int c = idx / K, k = idx - c * K;
                int g = ((c >> 4) << 8) + (w << 4) + (c & 15);
                d[c * S + k] = (_Float16)s[k * 768 + g];
            }
        }
        for (int idx = t; idx < 128 * 32; idx += THREADS) {
            int n = idx >> 5, k = idx & 31;
            lwdk[idx] = (k < 16) ? (_Float16)Wd[(w * 16 + k) * 128 + n] : (_Float16)0.f;
        }
        for (int idx = t; idx < 16 * 32; idx += THREADS) sxd[idx] = (_Float16)0.f;
        const float* bsrc[3] = {b0, b1, b2};
        for (int idx = t; idx < 288; idx += THREADS) {
            int l = idx / 96, r = idx - l * 96, which = r / 48, c = r - which * 48;
            int g = ((c >> 4) << 8) + (w << 4) + (c & 15);
            sb[l][which][c] = bsrc[l][which * 768 + g];
        }
        for (int idx = t; idx < 128; idx += THREADS) sbdf[idx] = bd[idx];
        for (int idx = t; idx < 2 * 128; idx += THREADS) {
            int cc = idx >> 7, p = idx & 127;
            unsigned v0 = pk(h_init[0 * 256 + 2 * p], h_init[0 * 256 + 2 * p + 1]);
            sh0[0][cc][p] = v0; sh0[1][cc][p] = v0;
            sh1[cc][p] = pk(h_init[1 * 256 + 2 * p], h_init[1 * 256 + 2 * p + 1]);
            sh2[cc][p] = pk(h_init[2 * 256 + 2 * p], h_init[2 * 256 + 2 * p + 1]);
        }
    }
    // finalize threads: t<48, layer = t>>4, chain = (t>>3)&1, unit-pair = t&7
    float hrA = 0.f, hrB = 0.f;
    if (t < 48) {
        int l = t >> 4, pl = t & 7;
        hrA = h_init[l * 256 + (w * 16 + 2 * pl)];
        hrB = h_init[l * 256 + (w * 16 + 2 * pl) + 1];
    }
    __syncthreads();

    auto store_g = [&](int l, f32x4 wa, f32x4 ua) {
        if (lane < 16) {
            #pragma unroll
            for (int r = 0; r < 2; ++r) {
                sgx[l][(wv * 16 + u16) * 4 + r] = wa[r];
                sgh[l][(wv * 16 + u16) * 4 + r] = ua[r];
            }
        }
    };
    // finalize layer l on threads (t>>4)==l; publish = single tagged u64 store
    auto do_final = [&](int l, unsigned (*ldst)[132], unsigned long long* garr,
                        unsigned tag, bool dox3, bool dox2) {
        if ((t >> 4) == l) {
            int cc = (t >> 3) & 1, pl = t & 7, gpi = w * 8 + pl;
            float hn2[2];
            float hcur[2] = {hrA, hrB};
            #pragma unroll
            for (int i = 0; i < 2; ++i) {
                int lu = 2 * pl + i;
                float gxz = sgx[l][(0 * 16 + lu) * 4 + cc] + sb[l][0][lu];
                float ghz = sgh[l][(0 * 16 + lu) * 4 + cc] + sb[l][1][lu];
                float gxr = sgx[l][(1 * 16 + lu) * 4 + cc] + sb[l][0][16 + lu];
                float ghr = sgh[l][(1 * 16 + lu) * 4 + cc] + sb[l][1][16 + lu];
                float gxn = sgx[l][(2 * 16 + lu) * 4 + cc] + sb[l][0][32 + lu];
                float ghn = sgh[l][(2 * 16 + lu) * 4 + cc] + sb[l][1][32 + lu];
                float z = sigmoidf_(gxz + ghz);
                float r = sigmoidf_(gxr + ghr);
                float n = tanhf(gxn + r * ghn);
                hn2[i] = z * hcur[i] + (1.f - z) * n;
            }
            hrA = hn2[0]; hrB = hn2[1];
            unsigned pv = pk(hn2[0], hn2[1]);
            ldst[cc][gpi] = pv;
            __hip_atomic_store(garr + (tag & 1) * 256 + cc * 128 + gpi,
                               ((unsigned long long)tag << 32) | (unsigned long long)pv,
                               __ATOMIC_RELAXED, __HIP_MEMORY_SCOPE_AGENT);
            if (dox2) {   // own slice of x2 = h1 + h0 (AR round B fusion)
                float2 h0p = upk(sh0[1][cc][gpi]);
                sx2[cc][gpi] = pk(hn2[0] + h0p.x, hn2[1] + h0p.y);
            }
            if (dox3) {   // own slice of x3 = h2 + x2 for K-split dense
                float2 x2p = upk(sx2[cc][gpi]);
                sxd[cc * 32 + 2 * pl]     = (_Float16)(hn2[0] + x2p.x);
                sxd[cc * 32 + 2 * pl + 1] = (_Float16)(hn2[1] + x2p.y);
            }
        }
    };
    auto dense_pub = [&](unsigned tag) {
        half8 a = *(const half8*)(const void*)(sxd + u16 * 32 + kg * 8);
        int nt0 = 2 * wv;
        half8 bA = *(const half8*)(const void*)(lwdk + (nt0 * 16 + u16) * 32 + kg * 8);
        half8 bB = *(const half8*)(const void*)(lwdk + ((nt0 + 1) * 16 + u16) * 32 + kg * 8);
        f32x4 z4l = {0.f, 0.f, 0.f, 0.f};
        f32x4 dA = __builtin_amdgcn_mfma_f32_16x16x32_f16(a, bA, z4l, 0, 0, 0);
        f32x4 dB = __builtin_amdgcn_mfma_f32_16x16x32_f16(a, bB, z4l, 0, 0, 0);
        if (lane < 16) {
            unsigned long long* base = g_pd + (tag & 1) * 4096 + (unsigned)w * 256;
            #pragma unroll
            for (int r = 0; r < 2; ++r) {
                union { float f; unsigned u; } cA, cB;
                cA.f = dA[r]; cB.f = dB[r];
                __hip_atomic_store(base + r * 128 + nt0 * 16 + u16,
                                   ((unsigned long long)tag << 32) | cA.u,
                                   __ATOMIC_RELAXED, __HIP_MEMORY_SCOPE_AGENT);
                __hip_atomic_store(base + r * 128 + (nt0 + 1) * 16 + u16,
                                   ((unsigned long long)tag << 32) | cB.u,
                                   __ATOMIC_RELAXED, __HIP_MEMORY_SCOPE_AGENT);
            }
        }
    };
    // batched pred gather (verified R11 form) — used at warmup->AR entry
    auto pred_gather = [&](unsigned tag, int row) {
        const int cc = t >> 7, o = t & 127;
        const unsigned long long* base = g_pd + (tag & 1) * 4096 + cc * 128 + o;
        unsigned long long v[16];
        #pragma unroll
        for (int src = 0; src < 16; ++src)
            v[src] = __hip_atomic_load(base + src * 256, __ATOMIC_RELAXED,
                                       __HIP_MEMORY_SCOPE_AGENT);
        #pragma unroll
        for (int src = 0; src < 16; ++src) {
            unsigned it = 0;
            while ((unsigned)(v[src] >> 32) < tag) {
                __builtin_amdgcn_s_sleep(1);
                v[src] = __hip_atomic_load(base + src * 256, __ATOMIC_RELAXED,
                                           __HIP_MEMORY_SCOPE_AGENT);
                if (++it > (1u << 20)) break;
            }
        }
        float s = sbdf[o];
        #pragma unroll
        for (int src = 0; src < 16; ++src) {
            union { unsigned u; float f; } cv; cv.u = (unsigned)v[src];
            s += cv.f;
        }
        spredf[cc][o] = s;
        __syncthreads();
        if (t < 128) {
            int c2 = t >> 6, p2 = t & 63;
            sx0[c2][p2] = pk(spredf[c2][2 * p2], spredf[c2][2 * p2 + 1]);
        }
        if (t < 16) {
            int c2 = t >> 3, dd = w * 8 + (t & 7);
            out[((size_t)(grp * NCH + c2) * T_OUT + row) * D_ + dd] = spredf[c2][dd];
        }
    };

    const f32x4 z4 = {0.f, 0.f, 0.f, 0.f};
    f32x4 ua0 = z4, ua1 = z4, ua2 = z4;

    // initial x0(0)
    if (t < 128) {
        int cc = t >> 6, p = t & 63;
        const float* ip = inputs + ((size_t)(grp * NCH + cc) * T_IN + 0) * D_ + 2 * p;
        const float* np = noise  + ((size_t)(grp * NCH + cc) * T_IN + 0) * D_ + 2 * p;
        sx0[cc][p] = pk(ip[0] + np[0], ip[1] + np[1]);
    }
    __syncthreads();

    // ================= PIPELINED WARMUP (+2 drain beats) =================
    // beat b: h0(b) [b<256], h1(b-1) [1<=b<=256], h2(b-2) [b>=2]
    // tags: h0(s) -> s+1, h1(s) -> s+1, h2(s) -> s+1; slot = tag&1
    for (int b = 0; b <= 257; ++b) {
        const int pcur = b & 1, pprev = (b + 1) & 1;
        if (wv < 3) {
            if (b < 256) {
                f32x4 wa = mm_k(&sx0[0][0] + ch2 * 68 + kg * 4,
                                lw0 + (wv * 16 + u16) * 136 + kg * 8, 4, z4);
                f32x4 ua = mm_k(&sh0[pprev][0][0] + ch2 * 132 + kg * 4,
                                lu0 + (wv * 16 + u16) * 264 + kg * 8, 8, z4);
                store_g(0, wa, ua);
            }
            if (b >= 1 && b <= 256) {
                f32x4 wa = mm_k(&sh0[pprev][0][0] + ch2 * 132 + kg * 4,
                                lw1 + (wv * 16 + u16) * 264 + kg * 8, 8, z4);
                f32x4 ua = mm_k(&sh1[0][0] + ch2 * 132 + kg * 4,
                                lu1 + (wv * 16 + u16) * 264 + kg * 8, 8, z4);
                store_g(1, wa, ua);
            }
            if (b >= 2) {
                f32x4 wa = mm_k(&sx2[0][0] + ch2 * 132 + kg * 4,
                                lw2 + (wv * 16 + u16) * 264 + kg * 8, 8, z4);
                f32x4 ua = mm_k(&sh2[0][0] + ch2 * 132 + kg * 4,
                                lu2 + (wv * 16 + u16) * 264 + kg * 8, 8, z4);
                store_g(2, wa, ua);
            }
        }
        __syncthreads();
        // finalize + tagged publish
        if (b < 256)            do_final(0, sh0[pcur], g_h0, (unsigned)(b + 1), false, false);
        if (b >= 1 && b <= 256) do_final(1, sh1, g_h1, (unsigned)b, false, false);
        if (b >= 2)             do_final(2, sh2, g_h2, (unsigned)(b - 1), b == 257, false);
        // input prefetch (hides HBM under polls)
        float i0 = 0.f, i1 = 0.f;
        if (b + 1 < 256 && t < 128) {
            int cc = t >> 6, p = t & 63;
            const float* ip = inputs + ((size_t)(grp * NCH + cc) * T_IN + (b + 1)) * D_ + 2 * p;
            const float* np = noise  + ((size_t)(grp * NCH + cc) * T_IN + (b + 1)) * D_ + 2 * p;
            i0 = ip[0] + np[0]; i1 = ip[1] + np[1];
        }
        // fused triple gather: issue all initial loads, then resolve
        {
            const bool act = (t < 240);
            const bool n0 = act && (b < 256);
            const bool n1 = act && (b >= 1 && b <= 256);
            const bool n2 = act && (b >= 2);
            int cc = 0, gpi = 0;
            const unsigned long long *p0 = nullptr, *p1 = nullptr, *p2 = nullptr;
            unsigned long long v0 = 0, v1 = 0, v2 = 0;
            if (act) {
                int i = t >> 4, rem = t & 15; cc = rem >> 3; int pl = rem & 7;
                int src = i + (i >= w);
                gpi = src * 8 + pl;
                const int off = cc * 128 + gpi;
                if (n0) { p0 = g_h0 + (((unsigned)(b + 1)) & 1) * 256 + off;
                          v0 = __hip_atomic_load(p0, __ATOMIC_RELAXED, __HIP_MEMORY_SCOPE_AGENT); }
                if (n1) { p1 = g_h1 + (((unsigned)b) & 1) * 256 + off;
                          v1 = __hip_atomic_load(p1, __ATOMIC_RELAXED, __HIP_MEMORY_SCOPE_AGENT); }
                if (n2) { p2 = g_h2 + (((unsigned)(b - 1)) & 1) * 256 + off;
                          v2 = __hip_atomic_load(p2, __ATOMIC_RELAXED, __HIP_MEMORY_SCOPE_AGENT); }
            }
            if (n0) {
                unsigned it = 0;
                while ((unsigned)(v0 >> 32) < (unsigned)(b + 1)) {
                    __builtin_amdgcn_s_sleep(1);
                    v0 = __hip_atomic_load(p0, __ATOMIC_RELAXED, __HIP_MEMORY_SCOPE_AGENT);
                    if (++it > (1u << 20)) break;
                }
                sh0[pcur][cc][gpi] = (unsigned)v0;
            }
            if (n1) {
                unsigned it = 0;
                while ((unsigned)(v1 >> 32) < (unsigned)b) {
                    __builtin_amdgcn_s_sleep(1);
                    v1 = __hip_atomic_load(p1, __ATOMIC_RELAXED, __HIP_MEMORY_SCOPE_AGENT);
                    if (++it > (1u << 20)) break;
                }
                sh1[cc][gpi] = (unsigned)v1;
            }
            if (n2) {
                unsigned it = 0;
                while ((unsigned)(v2 >> 32) < (unsigned)(b - 1)) {
                    __builtin_amdgcn_s_sleep(1);
                    v2 = __hip_atomic_load(p2, __ATOMIC_RELAXED, __HIP_MEMORY_SCOPE_AGENT);
                    if (++it > (1u << 20)) break;
                }
                sh2[cc][gpi] = (unsigned)v2;
            }
        }
        if (b + 1 < 256 && t < 128) sx0[t >> 6][t & 63] = pk(i0, i1);
        __syncthreads();
        if (b >= 1 && b <= 256) {   // sx2 = x2(b-1) = h0(b-1) + h1(b-1)
            int cc = t >> 7, p = t & 127;
            float2 a = upk(sh0[pprev][cc][p]);
            float2 bb = upk(sh1[cc][p]);
            sx2[cc][p] = pk(a.x + bb.x, a.y + bb.y);
            __syncthreads();
        }
        if (b == 257) {   // dense for pred(255) (tag 1), AR entry
            dense_pub(1);
            if (wv < 3)
                ua0 = mm_k(&sh0[1][0][0] + ch2 * 132 + kg * 4,
                           lu0 + (wv * 16 + u16) * 264 + kg * 8, 8, z4);
            pred_gather(1, 0);
            __syncthreads();
        }
    }

    // ================= AR PHASE (3 tagged rounds/step) =================
    for (int ts = T_IN; ts < NSTEP; ++ts) {
        const unsigned ht = (unsigned)(ts + 1);     // h tag this step
        const unsigned pt = (unsigned)(ts - 254);   // pred tag
        // ---- round A: layer 0 ----
        if (wv < 3) {
            f32x4 wa = mm_k(&sx0[0][0] + ch2 * 68 + kg * 4,
                            lw0 + (wv * 16 + u16) * 136 + kg * 8, 4, z4);
            store_g(0, wa, ua0);
        }
        __syncthreads();
        do_final(0, sh0[1], g_h0, ht, false, false);
        {   // fused gather h2(ts-1)+h0(ts): issue loads, ua1 under RTT, resolve
            const bool act = (t < 240);
            int cc = 0, gpi = 0;
            const unsigned long long *pA = nullptr, *pB = nullptr;
            unsigned long long vA = 0, vB = 0;
            if (act) {
                int i = t >> 4, rem = t & 15; cc = rem >> 3; int pl = rem & 7;
                int src = i + (i >= w);
                gpi = src * 8 + pl;
                const int off = cc * 128 + gpi;
                pA = g_h2 + ((ht - 1) & 1) * 256 + off;
                pB = g_h0 + (ht & 1) * 256 + off;
                vA = __hip_atomic_load(pA, __ATOMIC_RELAXED, __HIP_MEMORY_SCOPE_AGENT);
                vB = __hip_atomic_load(pB, __ATOMIC_RELAXED, __HIP_MEMORY_SCOPE_AGENT);
            }
            if (wv < 3)   // overlap: U1*h1(ts-1)
                ua1 = mm_k(&sh1[0][0] + ch2 * 132 + kg * 4,
                           lu1 + (wv * 16 + u16) * 264 + kg * 8, 8, z4);
            if (act) {
                unsigned it = 0;
                while ((unsigned)(vA >> 32) < ht - 1) {
                    __builtin_amdgcn_s_sleep(1);
                    vA = __hip_atomic_load(pA, __ATOMIC_RELAXED, __HIP_MEMORY_SCOPE_AGENT);
                    if (++it > (1u << 20)) break;
                }
                sh2[cc][gpi] = (unsigned)vA;
                it = 0;
                while ((unsigned)(vB >> 32) < ht) {
                    __builtin_amdgcn_s_sleep(1);
                    vB = __hip_atomic_load(pB, __ATOMIC_RELAXED, __HIP_MEMORY_SCOPE_AGENT);
                    if (++it > (1u << 20)) break;
                }
                sh0[1][cc][gpi] = (unsigned)vB;
            }
        }
        __syncthreads();
        // ---- round B: layer 1 ----
        if (wv < 3) {
            f32x4 wa = mm_k(&sh0[1][0][0] + ch2 * 132 + kg * 4,
                            lw1 + (wv * 16 + u16) * 264 + kg * 8, 8, z4);
            store_g(1, wa, ua1);
        }
        __syncthreads();
        do_final(1, sh1, g_h1, ht, false, true);   // dox2: own sx2 = h1+h0
        {   // fused gather h1(ts) + sx2 fusion: issue, ua2 under RTT, resolve
            const bool act = (t < 240);
            int cc = 0, gpi = 0;
            const unsigned long long* pB = nullptr;
            unsigned long long vB = 0;
            if (act) {
                int i = t >> 4, rem = t & 15; cc = rem >> 3; int pl = rem & 7;
                int src = i + (i >= w);
                gpi = src * 8 + pl;
                pB = g_h1 + (ht & 1) * 256 + cc * 128 + gpi;
                vB = __hip_atomic_load(pB, __ATOMIC_RELAXED, __HIP_MEMORY_SCOPE_AGENT);
            }
            if (wv < 3)   // overlap: U2*h2(ts-1)
                ua2 = mm_k(&sh2[0][0] + ch2 * 132 + kg * 4,
                           lu2 + (wv * 16 + u16) * 264 + kg * 8, 8, z4);
            if (act) {
                unsigned it = 0;
                while ((unsigned)(vB >> 32) < ht) {
                    __builtin_amdgcn_s_sleep(1);
                    vB = __hip_atomic_load(pB, __ATOMIC_RELAXED, __HIP_MEMORY_SCOPE_AGENT);
                    if (++it > (1u << 20)) break;
                }
                sh1[cc][gpi] = (unsigned)vB;
                float2 a = upk((unsigned)vB);
                float2 b0 = upk(sh0[1][cc][gpi]);
                sx2[cc][gpi] = pk(a.x + b0.x, a.y + b0.y);
            }
        }
        __syncthreads();
        // ---- round C: layer 2 + K-split dense ----
        if (wv < 3) {
            f32x4 wa = mm_k(&sx2[0][0] + ch2 * 132 + kg * 4,
                            lw2 + (wv * 16 + u16) * 264 + kg * 8, 8, z4);
            store_g(2, wa, ua2);
        }
        __syncthreads();
        do_final(2, sh2, g_h2, ht, true, false);
        __syncthreads();   // sxd visible
        dense_pub(pt);
        {   // pred gather: issue 16 loads, ua0 under RTT, resolve+sum
            const int cc = t >> 7, o = t & 127;
            const unsigned long long* base = g_pd + (pt & 1) * 4096 + cc * 128 + o;
            unsigned long long v[16];
            #pragma unroll
            for (int src = 0; src < 16; ++src)
                v[src] = __hip_atomic_load(base + src * 256, __ATOMIC_RELAXED,
                                           __HIP_MEMORY_SCOPE_AGENT);
            if (wv < 3)   // overlap: U0*h0(ts) for next step
                ua0 = mm_k(&sh0[1][0][0] + ch2 * 132 + kg * 4,
                           lu0 + (wv * 16 + u16) * 264 + kg * 8, 8, z4);
            #pragma unroll
            for (int src = 0; src < 16; ++src) {
                unsigned it = 0;
                while ((unsigned)(v[src] >> 32) < pt) {
                    __builtin_amdgcn_s_sleep(1);
                    v[src] = __hip_atomic_load(base + src * 256, __ATOMIC_RELAXED,
                                               __HIP_MEMORY_SCOPE_AGENT);
                    if (++it > (1u << 20)) break;
                }
            }
            float s = sbdf[o];
            #pragma unroll
            for (int src = 0; src < 16; ++src) {
                union { unsigned u; float f; } cv; cv.u = (unsigned)v[src];
                s += cv.f;
            }
            spredf[cc][o] = s;
            __syncthreads();
            if (t < 128) {
                int c2 = t >> 6, p2 = t & 63;
                sx0[c2][p2] = pk(spredf[c2][2 * p2], spredf[c2][2 * p2 + 1]);
            }
            if (t < 16) {
                int c2 = t >> 3, dd = w * 8 + (t & 7);
                out[((size_t)(grp * NCH + c2) * T_OUT + (ts - 255)) * D_ + dd] = spredf[c2][dd];
            }
        }
        __syncthreads();
    }
}

// ---- fallback: round-1 verified fp32 kernel (tiny/absent ws) ----
__global__ __launch_bounds__(768) void gru_ar_fp32(
    const float* __restrict__ inputs, const float* __restrict__ noise,
    const float* __restrict__ h_init,
    const float* __restrict__ W0, const float* __restrict__ U0, const float* __restrict__ b0,
    const float* __restrict__ W1, const float* __restrict__ U1, const float* __restrict__ b1,
    const float* __restrict__ W2, const float* __restrict__ U2, const float* __restrict__ b2,
    const float* __restrict__ Wd, const float* __restrict__ bd,
    float* __restrict__ out)
{
    const int b = blockIdx.x;
    const int j = threadIdx.x;
    __shared__ float s_x[U_];
    __shared__ float s_h[3][U_];
    __shared__ float s_gz[U_], s_gr[U_], s_gxn[U_], s_ghn[U_];
    __shared__ float s_pred[D_];
    if (j < U_) {
        s_h[0][j] = h_init[0 * U_ + j];
        s_h[1][j] = h_init[1 * U_ + j];
        s_h[2][j] = h_init[2 * U_ + j];
    }
    __syncthreads();
    const float* Ws[3]  = {W0, W1, W2};
    const float* Us[3]  = {U0, U1, U2};
    const float* bss[3] = {b0, b1, b2};
    for (int ts = 0; ts < NSTEP; ++ts) {
        if (j < D_) {
            if (ts < T_IN) {
                const int idx = (b * T_IN + ts) * D_ + j;
                s_x[j] = inputs[idx] + noise[idx];
            } else s_x[j] = s_pred[j];
        }
        __syncthreads();
        #pragma unroll
        for (int l = 0; l < 3; ++l) {
            const int K = (l == 0) ? D_ : U_;
            const float* W = Ws[l]; const float* Urec = Us[l]; const float* bias = bss[l];
            float gx = bias[j];
            for (int k = 0; k < K; ++k) gx = fmaf(s_x[k], W[k * 768 + j], gx);
            float gh = bias[768 + j];
            for (int k = 0; k < U_; ++k) gh = fmaf(s_h[l][k], Urec[k * 768 + j], gh);
            if (j < U_)            s_gz[j] = gx + gh;
            else if (j < 2 * U_)   s_gr[j - U_] = gx + gh;
            else { s_gxn[j - 2 * U_] = gx; s_ghn[j - 2 * U_] = gh; }
            __syncthreads();
            if (j < U_) {
                const float z = sigmoidf_(s_gz[j]);
                const float r = sigmoidf_(s_gr[j]);
                const float n = tanhf(s_gxn[j] + r * s_ghn[j]);
                const float h_new = z * s_h[l][j] + (1.0f - z) * n;
                s_h[l][j] = h_new;
                s_x[j] = (l == 0) ? h_new : (h_new + s_x[j]);
            }
            __syncthreads();
        }
        if (ts >= T_IN - 1) {
            if (j < D_) {
                float p = bd[j];
                for (int k = 0; k < U_; ++k) p = fmaf(s_x[k], Wd[k * D_ + j], p);
                s_pred[j] = p;
                out[(b * T_OUT + (ts - (T_IN - 1))) * D_ + j] = p;
            }
            __syncthreads();
        }
    }
}

extern "C" void kernel_launch(void* const* d_in, const int* in_sizes, int n_in,
                              void* d_out, int out_size, void* d_ws, size_t ws_size,
                              hipStream_t stream) {
    (void)in_sizes; (void)n_in; (void)out_size;
    const float* inputs = (const float*)d_in[0];
    const float* noise  = (const float*)d_in[1];
    const float* h_init = (const float*)d_in[2];
    const float* W0 = (const float*)d_in[3];
    const float* U0 = (const float*)d_in[4];
    const float* b0 = (const float*)d_in[5];
    const float* W1 = (const float*)d_in[6];
    const float* U1 = (const float*)d_in[7];
    const float* b1 = (const float*)d_in[8];
    const float* W2 = (const float*)d_in[9];
    const float* U2 = (const float*)d_in[10];
    const float* b2 = (const float*)d_in[11];
    const float* Wd = (const float*)d_in[12];
    const float* bd = (const float*)d_in[13];
    float* out = (float*)d_out;

    if (ws_size >= (size_t)WS_NEED) {
        const int n = NGRP * GRPSTRIDE64 * 2;   // u32 words
        zero_ws<<<(n + 255) / 256, 256, 0, stream>>>((unsigned*)d_ws, n);
        gru_dist<<<NGRP * NWG, THREADS, 0, stream>>>(
            inputs, noise, h_init, W0, U0, b0, W1, U1, b1, W2, U2, b2, Wd, bd,
            (unsigned long long*)d_ws, out);
    } else {
        gru_ar_fp32<<<32, 768, 0, stream>>>(
            inputs, noise, h_init, W0, U0, b0, W1, U1, b1, W2, U2, b2, Wd, bd, out);
    }
}

// Round 13
// 3051.890 us; speedup vs baseline: 1.1599x; 1.1599x over previous
//
#include <hip/hip_runtime.h>
#include <math.h>

// Problem constants
#define T_IN   256
#define T_OUT  256
#define D_     128
#define U_     256
#define NSTEP  511

// 16 groups x 2 chains; 16 WGs per group; 256 threads/WG; 256 WGs total (1/CU)
#define NWG    16
#define NCH    2
#define NGRP   16
#define THREADS 256

// ws per group in u64 units (tagged words: hi32 = tag, lo32 = payload):
//   g_h0 [2 slot][2 ch][128]  @ 0
//   g_h1                      @ 512
//   g_h2                      @ 1024
//   g_pd [2 slot][16 src][2 ch][128] @ 1536   (fp32 dense partials)
// Verified-best (R11): batched pred gather; R6 layout/protocol everywhere.
// R12 lesson: do NOT issue gather loads before the overlap matmul — the
// wait is producer-publish-visibility; early polls only add LLC traffic.
#define G64_H0   0
#define G64_H1   512
#define G64_H2   1024
#define G64_PD   1536
#define GRPSTRIDE64 10240
#define WS_NEED  (NGRP * GRPSTRIDE64 * 8)   // 1,310,720 B (ws_size >= 2.23MB known ok)

typedef _Float16 half8 __attribute__((ext_vector_type(8)));
typedef float    f32x4 __attribute__((ext_vector_type(4)));

__device__ __forceinline__ float sigmoidf_(float x) { return 1.0f / (1.0f + __expf(-x)); }
__device__ __forceinline__ unsigned pk(float a, float b) {
    union { _Float16 h[2]; unsigned u; } v;
    v.h[0] = (_Float16)a; v.h[1] = (_Float16)b; return v.u;
}
__device__ __forceinline__ float2 upk(unsigned x) {
    union { unsigned u; _Float16 h[2]; } v; v.u = x;
    return make_float2((float)v.h[0], (float)v.h[1]);
}

__global__ void zero_ws(unsigned* p, int n) {
    int i = blockIdx.x * 256 + threadIdx.x;
    if (i < n) p[i] = 0;
}

__device__ __forceinline__ f32x4 mm_k(const unsigned* xb, const _Float16* wb,
                                      int nks, f32x4 acc) {
    #pragma unroll
    for (int ks = 0; ks < nks; ++ks) {
        half8 a = *(const half8*)(const void*)(xb + ks * 16);
        half8 b = *(const half8*)(const void*)(wb + ks * 32);
        acc = __builtin_amdgcn_mfma_f32_16x16x32_f16(a, b, acc, 0, 0, 0);
    }
    return acc;
}

__global__ __launch_bounds__(THREADS) void gru_dist(
    const float* __restrict__ inputs, const float* __restrict__ noise,
    const float* __restrict__ h_init,
    const float* __restrict__ W0, const float* __restrict__ U0, const float* __restrict__ b0,
    const float* __restrict__ W1, const float* __restrict__ U1, const float* __restrict__ b1,
    const float* __restrict__ W2, const float* __restrict__ U2, const float* __restrict__ b2,
    const float* __restrict__ Wd, const float* __restrict__ bd,
    unsigned long long* __restrict__ ws, float* __restrict__ out)
{
    const int bid  = blockIdx.x;
    const int grp  = bid & 15;      // groups interleaved so a group's WGs share an XCD (heuristic)
    const int w    = bid >> 4;      // wg-in-group 0..15
    const int t    = threadIdx.x;
    const int lane = t & 63;
    const int wv   = t >> 6;
    const int u16  = lane & 15, kg = lane >> 4, ch2 = u16 & 1;

    // ---- LDS (~158 KB) ----
    __shared__ __align__(16) _Float16 lw0[48 * 136];
    __shared__ __align__(16) _Float16 lu0[48 * 264];
    __shared__ __align__(16) _Float16 lw1[48 * 264];
    __shared__ __align__(16) _Float16 lu1[48 * 264];
    __shared__ __align__(16) _Float16 lw2[48 * 264];
    __shared__ __align__(16) _Float16 lu2[48 * 264];
    __shared__ __align__(16) _Float16 lwdk[128 * 32];  // [n][own-k 0..31], k>=16 zero
    __shared__ __align__(16) _Float16 sxd[16 * 32];    // dense A (rows 0,1 = chains)
    __shared__ __align__(16) unsigned sx0[NCH][68];
    __shared__ __align__(16) unsigned sh0[2][NCH][132];
    __shared__ __align__(16) unsigned sh1[NCH][132];
    __shared__ __align__(16) unsigned sh2[NCH][132];
    __shared__ __align__(16) unsigned sx2[NCH][132];
    __shared__ float sgx[3][192];
    __shared__ float sgh[3][192];
    __shared__ float sb[3][2][48];
    __shared__ float sbdf[128];
    __shared__ float spredf[NCH][128];

    unsigned long long* gbase = ws + (size_t)grp * GRPSTRIDE64;
    unsigned long long* g_h0 = gbase + G64_H0;
    unsigned long long* g_h1 = gbase + G64_H1;
    unsigned long long* g_h2 = gbase + G64_H2;
    unsigned long long* g_pd = gbase + G64_PD;

    // ---- one-time preload ----
    {
        const float* srcs[6] = {W0, U0, W1, U1, W2, U2};
        _Float16*    dsts[6] = {lw0, lu0, lw1, lu1, lw2, lu2};
        const int Ks[6] = {128, 256, 256, 256, 256, 256};
        const int Ss[6] = {136, 264, 264, 264, 264, 264};
        for (int m = 0; m < 6; ++m) {
            const float* s = srcs[m]; _Float16* d = dsts[m];
            const int K = Ks[m], S = Ss[m];
            for (int idx = t; idx < 48 * K; idx += THREADS) {
                int c = idx / K, k = idx - c * K;
                int g = ((c >> 4) << 8) + (w << 4) + (c & 15);
                d[c * S + k] = (_Float16)s[k * 768 + g];
            }
        }
        for (int idx = t; idx < 128 * 32; idx += THREADS) {
            int n = idx >> 5, k = idx & 31;
            lwdk[idx] = (k < 16) ? (_Float16)Wd[(w * 16 + k) * 128 + n] : (_Float16)0.f;
        }
        for (int idx = t; idx < 16 * 32; idx += THREADS) sxd[idx] = (_Float16)0.f;
        const float* bsrc[3] = {b0, b1, b2};
        for (int idx = t; idx < 288; idx += THREADS) {
            int l = idx / 96, r = idx - l * 96, which = r / 48, c = r - which * 48;
            int g = ((c >> 4) << 8) + (w << 4) + (c & 15);
            sb[l][which][c] = bsrc[l][which * 768 + g];
        }
        for (int idx = t; idx < 128; idx += THREADS) sbdf[idx] = bd[idx];
        for (int idx = t; idx < 2 * 128; idx += THREADS) {
            int cc = idx >> 7, p = idx & 127;
            unsigned v0 = pk(h_init[0 * 256 + 2 * p], h_init[0 * 256 + 2 * p + 1]);
            sh0[0][cc][p] = v0; sh0[1][cc][p] = v0;
            sh1[cc][p] = pk(h_init[1 * 256 + 2 * p], h_init[1 * 256 + 2 * p + 1]);
            sh2[cc][p] = pk(h_init[2 * 256 + 2 * p], h_init[2 * 256 + 2 * p + 1]);
        }
    }
    // finalize threads: t<48, layer = t>>4, chain = (t>>3)&1, unit-pair = t&7
    float hrA = 0.f, hrB = 0.f;
    if (t < 48) {
        int l = t >> 4, pl = t & 7;
        hrA = h_init[l * 256 + (w * 16 + 2 * pl)];
        hrB = h_init[l * 256 + (w * 16 + 2 * pl) + 1];
    }
    __syncthreads();

    // ---- tagged-P2P primitives (1 IF round-trip per comm round) ----
    auto gather_tagged = [&](const unsigned long long* garr, unsigned (*lds)[132],
                             unsigned tag) {
        const unsigned long long* base = garr + (tag & 1) * 256;
        for (int idx = t; idx < 240; idx += THREADS) {
            int i = idx >> 4, rem = idx & 15, cc = rem >> 3, pl = rem & 7;
            int src = i + (i >= w);
            int gpi = src * 8 + pl;
            const unsigned long long* p = base + cc * 128 + gpi;
            unsigned long long v = __hip_atomic_load(p, __ATOMIC_RELAXED,
                                                     __HIP_MEMORY_SCOPE_AGENT);
            unsigned it = 0;
            while ((unsigned)(v >> 32) < tag) {
                __builtin_amdgcn_s_sleep(1);
                v = __hip_atomic_load(p, __ATOMIC_RELAXED, __HIP_MEMORY_SCOPE_AGENT);
                if (++it > (1u << 20)) break;   // loud corruption beats a hang
            }
            lds[cc][gpi] = (unsigned)v;
        }
    };
    auto store_g = [&](int l, f32x4 wa, f32x4 ua) {
        if (lane < 16) {
            #pragma unroll
            for (int r = 0; r < 2; ++r) {
                sgx[l][(wv * 16 + u16) * 4 + r] = wa[r];
                sgh[l][(wv * 16 + u16) * 4 + r] = ua[r];
            }
        }
    };
    // finalize layer l on threads (t>>4)==l; publish = single tagged u64 store
    auto do_final = [&](int l, unsigned (*ldst)[132], unsigned long long* garr,
                        unsigned tag, bool dox3) {
        if ((t >> 4) == l) {
            int cc = (t >> 3) & 1, pl = t & 7, gpi = w * 8 + pl;
            float hn2[2];
            float hcur[2] = {hrA, hrB};
            #pragma unroll
            for (int i = 0; i < 2; ++i) {
                int lu = 2 * pl + i;
                float gxz = sgx[l][(0 * 16 + lu) * 4 + cc] + sb[l][0][lu];
                float ghz = sgh[l][(0 * 16 + lu) * 4 + cc] + sb[l][1][lu];
                float gxr = sgx[l][(1 * 16 + lu) * 4 + cc] + sb[l][0][16 + lu];
                float ghr = sgh[l][(1 * 16 + lu) * 4 + cc] + sb[l][1][16 + lu];
                float gxn = sgx[l][(2 * 16 + lu) * 4 + cc] + sb[l][0][32 + lu];
                float ghn = sgh[l][(2 * 16 + lu) * 4 + cc] + sb[l][1][32 + lu];
                float z = sigmoidf_(gxz + ghz);
                float r = sigmoidf_(gxr + ghr);
                float n = tanhf(gxn + r * ghn);
                hn2[i] = z * hcur[i] + (1.f - z) * n;
            }
            hrA = hn2[0]; hrB = hn2[1];
            unsigned pv = pk(hn2[0], hn2[1]);
            ldst[cc][gpi] = pv;
            __hip_atomic_store(garr + (tag & 1) * 256 + cc * 128 + gpi,
                               ((unsigned long long)tag << 32) | (unsigned long long)pv,
                               __ATOMIC_RELAXED, __HIP_MEMORY_SCOPE_AGENT);
            if (dox3) {
                float2 x2p = upk(sx2[cc][gpi]);
                sxd[cc * 32 + 2 * pl]     = (_Float16)(hn2[0] + x2p.x);
                sxd[cc * 32 + 2 * pl + 1] = (_Float16)(hn2[1] + x2p.y);
            }
        }
    };
    auto dense_pub = [&](unsigned tag) {
        half8 a = *(const half8*)(const void*)(sxd + u16 * 32 + kg * 8);
        int nt0 = 2 * wv;
        half8 bA = *(const half8*)(const void*)(lwdk + (nt0 * 16 + u16) * 32 + kg * 8);
        half8 bB = *(const half8*)(const void*)(lwdk + ((nt0 + 1) * 16 + u16) * 32 + kg * 8);
        f32x4 z4l = {0.f, 0.f, 0.f, 0.f};
        f32x4 dA = __builtin_amdgcn_mfma_f32_16x16x32_f16(a, bA, z4l, 0, 0, 0);
        f32x4 dB = __builtin_amdgcn_mfma_f32_16x16x32_f16(a, bB, z4l, 0, 0, 0);
        if (lane < 16) {
            unsigned long long* base = g_pd + (tag & 1) * 4096 + (unsigned)w * 256;
            #pragma unroll
            for (int r = 0; r < 2; ++r) {
                union { float f; unsigned u; } cA, cB;
                cA.f = dA[r]; cB.f = dB[r];
                __hip_atomic_store(base + r * 128 + nt0 * 16 + u16,
                                   ((unsigned long long)tag << 32) | cA.u,
                                   __ATOMIC_RELAXED, __HIP_MEMORY_SCOPE_AGENT);
                __hip_atomic_store(base + r * 128 + (nt0 + 1) * 16 + u16,
                                   ((unsigned long long)tag << 32) | cB.u,
                                   __ATOMIC_RELAXED, __HIP_MEMORY_SCOPE_AGENT);
            }
        }
    };
    // batched tagged gather — issue all 16 loads (independent, pipelined),
    // then re-poll only stragglers. Addresses & FP sum order identical to R6.
    auto pred_gather = [&](unsigned tag, int row) {
        const int cc = t >> 7, o = t & 127;
        const unsigned long long* base = g_pd + (tag & 1) * 4096 + cc * 128 + o;
        unsigned long long v[16];
        #pragma unroll
        for (int src = 0; src < 16; ++src)
            v[src] = __hip_atomic_load(base + src * 256, __ATOMIC_RELAXED,
                                       __HIP_MEMORY_SCOPE_AGENT);
        #pragma unroll
        for (int src = 0; src < 16; ++src) {
            unsigned it = 0;
            while ((unsigned)(v[src] >> 32) < tag) {
                __builtin_amdgcn_s_sleep(1);
                v[src] = __hip_atomic_load(base + src * 256, __ATOMIC_RELAXED,
                                           __HIP_MEMORY_SCOPE_AGENT);
                if (++it > (1u << 20)) break;   // loud corruption beats a hang
            }
        }
        float s = sbdf[o];
        #pragma unroll
        for (int src = 0; src < 16; ++src) {
            union { unsigned u; float f; } cv; cv.u = (unsigned)v[src];
            s += cv.f;
        }
        spredf[cc][o] = s;
        __syncthreads();
        if (t < 128) {
            int c2 = t >> 6, p2 = t & 63;
            sx0[c2][p2] = pk(spredf[c2][2 * p2], spredf[c2][2 * p2 + 1]);
        }
        if (t < 16) {
            int c2 = t >> 3, dd = w * 8 + (t & 7);
            out[((size_t)(grp * NCH + c2) * T_OUT + row) * D_ + dd] = spredf[c2][dd];
        }
    };

    const f32x4 z4 = {0.f, 0.f, 0.f, 0.f};
    f32x4 ua0 = z4, ua1 = z4, ua2 = z4;

    // initial x0(0)
    if (t < 128) {
        int cc = t >> 6, p = t & 63;
        const float* ip = inputs + ((size_t)(grp * NCH + cc) * T_IN + 0) * D_ + 2 * p;
        const float* np = noise  + ((size_t)(grp * NCH + cc) * T_IN + 0) * D_ + 2 * p;
        sx0[cc][p] = pk(ip[0] + np[0], ip[1] + np[1]);
    }
    __syncthreads();

    // ================= PIPELINED WARMUP (+2 drain beats) =================
    // beat b: h0(b) [b<256], h1(b-1) [1<=b<=256], h2(b-2) [b>=2]
    // tags: h0(s) -> s+1, h1(s) -> s+1, h2(s) -> s+1; slot = tag&1
    for (int b = 0; b <= 257; ++b) {
        const int pcur = b & 1, pprev = (b + 1) & 1;
        if (wv < 3) {
            if (b < 256) {
                f32x4 wa = mm_k(&sx0[0][0] + ch2 * 68 + kg * 4,
                                lw0 + (wv * 16 + u16) * 136 + kg * 8, 4, z4);
                f32x4 ua = mm_k(&sh0[pprev][0][0] + ch2 * 132 + kg * 4,
                                lu0 + (wv * 16 + u16) * 264 + kg * 8, 8, z4);
                store_g(0, wa, ua);
            }
            if (b >= 1 && b <= 256) {
                f32x4 wa = mm_k(&sh0[pprev][0][0] + ch2 * 132 + kg * 4,
                                lw1 + (wv * 16 + u16) * 264 + kg * 8, 8, z4);
                f32x4 ua = mm_k(&sh1[0][0] + ch2 * 132 + kg * 4,
                                lu1 + (wv * 16 + u16) * 264 + kg * 8, 8, z4);
                store_g(1, wa, ua);
            }
            if (b >= 2) {
                f32x4 wa = mm_k(&sx2[0][0] + ch2 * 132 + kg * 4,
                                lw2 + (wv * 16 + u16) * 264 + kg * 8, 8, z4);
                f32x4 ua = mm_k(&sh2[0][0] + ch2 * 132 + kg * 4,
                                lu2 + (wv * 16 + u16) * 264 + kg * 8, 8, z4);
                store_g(2, wa, ua);
            }
        }
        __syncthreads();
        // finalize + tagged publish
        if (b < 256)            do_final(0, sh0[pcur], g_h0, (unsigned)(b + 1), false);
        if (b >= 1 && b <= 256) do_final(1, sh1, g_h1, (unsigned)b, false);
        if (b >= 2)             do_final(2, sh2, g_h2, (unsigned)(b - 1), b == 257);
        // input prefetch (hides HBM under poll)
        float i0 = 0.f, i1 = 0.f;
        if (b + 1 < 256 && t < 128) {
            int cc = t >> 6, p = t & 63;
            const float* ip = inputs + ((size_t)(grp * NCH + cc) * T_IN + (b + 1)) * D_ + 2 * p;
            const float* np = noise  + ((size_t)(grp * NCH + cc) * T_IN + (b + 1)) * D_ + 2 * p;
            i0 = ip[0] + np[0]; i1 = ip[1] + np[1];
        }
        // poll-gathers (data rides with the tag word)
        if (b < 256)            gather_tagged(g_h0, sh0[pcur], (unsigned)(b + 1));
        if (b >= 1 && b <= 256) gather_tagged(g_h1, sh1, (unsigned)b);
        if (b >= 2)             gather_tagged(g_h2, sh2, (unsigned)(b - 1));
        if (b + 1 < 256 && t < 128) sx0[t >> 6][t & 63] = pk(i0, i1);
        __syncthreads();
        if (b >= 1 && b <= 256) {   // sx2 = x2(b-1) = h0(b-1) + h1(b-1)
            int cc = t >> 7, p = t & 127;
            float2 a = upk(sh0[pprev][cc][p]);
            float2 bb = upk(sh1[cc][p]);
            sx2[cc][p] = pk(a.x + bb.x, a.y + bb.y);
            __syncthreads();
        }
        if (b == 257) {   // dense for pred(255) (tag 1), AR entry
            dense_pub(1);
            if (wv < 3)
                ua0 = mm_k(&sh0[1][0][0] + ch2 * 132 + kg * 4,
                           lu0 + (wv * 16 + u16) * 264 + kg * 8, 8, z4);
            pred_gather(1, 0);
            __syncthreads();
        }
    }

    // ================= AR PHASE (3 tagged rounds/step) =================
    for (int ts = T_IN; ts < NSTEP; ++ts) {
        const unsigned ht = (unsigned)(ts + 1);     // h tag this step
        const unsigned pt = (unsigned)(ts - 254);   // pred tag
        // ---- round A: layer 0 ----
        if (wv < 3) {
            f32x4 wa = mm_k(&sx0[0][0] + ch2 * 68 + kg * 4,
                            lw0 + (wv * 16 + u16) * 136 + kg * 8, 4, z4);
            store_g(0, wa, ua0);
        }
        __syncthreads();
        do_final(0, sh0[1], g_h0, ht, false);
        if (wv < 3)   // overlap: U1*h1(ts-1)
            ua1 = mm_k(&sh1[0][0] + ch2 * 132 + kg * 4,
                       lu1 + (wv * 16 + u16) * 264 + kg * 8, 8, z4);
        gather_tagged(g_h2, sh2, ht - 1);   // deferred h2(ts-1)
        gather_tagged(g_h0, sh0[1], ht);
        __syncthreads();
        // ---- round B: layer 1 ----
        if (wv < 3) {
            f32x4 wa = mm_k(&sh0[1][0][0] + ch2 * 132 + kg * 4,
                            lw1 + (wv * 16 + u16) * 264 + kg * 8, 8, z4);
            store_g(1, wa, ua1);
        }
        __syncthreads();
        do_final(1, sh1, g_h1, ht, false);
        if (wv < 3)   // overlap: U2*h2(ts-1)
            ua2 = mm_k(&sh2[0][0] + ch2 * 132 + kg * 4,
                       lu2 + (wv * 16 + u16) * 264 + kg * 8, 8, z4);
        gather_tagged(g_h1, sh1, ht);
        __syncthreads();
        {   // sx2 = h0(ts) + h1(ts)
            int cc = t >> 7, p = t & 127;
            float2 a = upk(sh0[1][cc][p]);
            float2 bb = upk(sh1[cc][p]);
            sx2[cc][p] = pk(a.x + bb.x, a.y + bb.y);
        }
        __syncthreads();
        // ---- round C: layer 2 + K-split dense ----
        if (wv < 3) {
            f32x4 wa = mm_k(&sx2[0][0] + ch2 * 132 + kg * 4,
                            lw2 + (wv * 16 + u16) * 264 + kg * 8, 8, z4);
            store_g(2, wa, ua2);
        }
        __syncthreads();
        do_final(2, sh2, g_h2, ht, true);
        __syncthreads();   // sxd visible
        dense_pub(pt);
        if (wv < 3)   // overlap: U0*h0(ts) for next step
            ua0 = mm_k(&sh0[1][0][0] + ch2 * 132 + kg * 4,
                       lu0 + (wv * 16 + u16) * 264 + kg * 8, 8, z4);
        pred_gather(pt, ts - 255);
        __syncthreads();
    }
}

// ---- fallback: round-1 verified fp32 kernel (tiny/absent ws) ----
__global__ __launch_bounds__(768) void gru_ar_fp32(
    const float* __restrict__ inputs, const float* __restrict__ noise,
    const float* __restrict__ h_init,
    const float* __restrict__ W0, const float* __restrict__ U0, const float* __restrict__ b0,
    const float* __restrict__ W1, const float* __restrict__ U1, const float* __restrict__ b1,
    const float* __restrict__ W2, const float* __restrict__ U2, const float* __restrict__ b2,
    const float* __restrict__ Wd, const float* __restrict__ bd,
    float* __restrict__ out)
{
    const int b = blockIdx.x;
    const int j = threadIdx.x;
    __shared__ float s_x[U_];
    __shared__ float s_h[3][U_];
    __shared__ float s_gz[U_], s_gr[U_], s_gxn[U_], s_ghn[U_];
    __shared__ float s_pred[D_];
    if (j < U_) {
        s_h[0][j] = h_init[0 * U_ + j];
        s_h[1][j] = h_init[1 * U_ + j];
        s_h[2][j] = h_init[2 * U_ + j];
    }
    __syncthreads();
    const float* Ws[3]  = {W0, W1, W2};
    const float* Us[3]  = {U0, U1, U2};
    const float* bss[3] = {b0, b1, b2};
    for (int ts = 0; ts < NSTEP; ++ts) {
        if (j < D_) {
            if (ts < T_IN) {
                const int idx = (b * T_IN + ts) * D_ + j;
                s_x[j] = inputs[idx] + noise[idx];
            } else s_x[j] = s_pred[j];
        }
        __syncthreads();
        #pragma unroll
        for (int l = 0; l < 3; ++l) {
            const int K = (l == 0) ? D_ : U_;
            const float* W = Ws[l]; const float* Urec = Us[l]; const float* bias = bss[l];
            float gx = bias[j];
            for (int k = 0; k < K; ++k) gx = fmaf(s_x[k], W[k * 768 + j], gx);
            float gh = bias[768 + j];
            for (int k = 0; k < U_; ++k) gh = fmaf(s_h[l][k], Urec[k * 768 + j], gh);
            if (j < U_)            s_gz[j] = gx + gh;
            else if (j < 2 * U_)   s_gr[j - U_] = gx + gh;
            else { s_gxn[j - 2 * U_] = gx; s_ghn[j - 2 * U_] = gh; }
            __syncthreads();
            if (j < U_) {
                const float z = sigmoidf_(s_gz[j]);
                const float r = sigmoidf_(s_gr[j]);
                const float n = tanhf(s_gxn[j] + r * s_ghn[j]);
                const float h_new = z * s_h[l][j] + (1.0f - z) * n;
                s_h[l][j] = h_new;
                s_x[j] = (l == 0) ? h_new : (h_new + s_x[j]);
            }
            __syncthreads();
        }
        if (ts >= T_IN - 1) {
            if (j < D_) {
                float p = bd[j];
                for (int k = 0; k < U_; ++k) p = fmaf(s_x[k], Wd[k * D_ + j], p);
                s_pred[j] = p;
                out[(b * T_OUT + (ts - (T_IN - 1))) * D_ + j] = p;
            }
            __syncthreads();
        }
    }
}

extern "C" void kernel_launch(void* const* d_in, const int* in_sizes, int n_in,
                              void* d_out, int out_size, void* d_ws, size_t ws_size,
                              hipStream_t stream) {
    (void)in_sizes; (void)n_in; (void)out_size;
    const float* inputs = (const float*)d_in[0];
    const float* noise  = (const float*)d_in[1];
    const float* h_init = (const float*)d_in[2];
    const float* W0 = (const float*)d_in[3];
    const float* U0 = (const float*)d_in[4];
    const float* b0 = (const float*)d_in[5];
    const float* W1 = (const float*)d_in[6];
    const float* U1 = (const float*)d_in[7];
    const float* b1 = (const float*)d_in[8];
    const float* W2 = (const float*)d_in[9];
    const float* U2 = (const float*)d_in[10];
    const float* b2 = (const float*)d_in[11];
    const float* Wd = (const float*)d_in[12];
    const float* bd = (const float*)d_in[13];
    float* out = (float*)d_out;

    if (ws_size >= (size_t)WS_NEED) {
        const int n = NGRP * GRPSTRIDE64 * 2;   // u32 words
        zero_ws<<<(n + 255) / 256, 256, 0, stream>>>((unsigned*)d_ws, n);
        gru_dist<<<NGRP * NWG, THREADS, 0, stream>>>(
            inputs, noise, h_init, W0, U0, b0, W1, U1, b1, W2, U2, b2, Wd, bd,
            (unsigned long long*)d_ws, out);
    } else {
        gru_ar_fp32<<<32, 768, 0, stream>>>(
            inputs, noise, h_init, W0, U0, b0, W1, U1, b1, W2, U2, b2, Wd, bd, out);
    }
}